// Round 7
// baseline (257.676 us; speedup 1.0000x reference)
//
#include <hip/hip_runtime.h>
#include <math.h>

// GaussianAdjacencyMatrix: out[b,i,j] = m*exp(-||x_i-x_j||^2/sigma^2) / (row_sum + 1e-8)
// B=8, N=2048, D=3.
//
// v7: TWO-PASS split — turn the one read+write kernel into two pure streams.
//   Diagnosis: R0/R2/R4/R6 (four structures, occ 39-100%) all stuck at ~80 us,
//   ~2.5 TB/s, while pure-write fill hits 6.6 TB/s and VALU totals <5 us.
//   Shared invariant: each wave interleaves HBM reads and HBM writes around the
//   row-sum dependency in one in-order vmcnt stream -> waiting for row k+1's
//   loads transitively waits on row k's store retirement; read and write
//   streams convoy instead of overlapping.
//   K1: masks -> row sums (pure 134 MB read stream + 64 KB sum writes to d_ws).
//   K2: masks (L3-hot from K1; 256 MB L3 > 134 MB) -> recompute exp2 -> scale
//       -> NT store (NT: don't evict masks from L3). No reduce, no cross-lane.
//   Exp recomputed in K2: <1 us total VALU — cheap price for stream purity.
//
// Softmax invariance (validated R4-R6, absmax 1.2e-4): drop the row-constant
// factor exp(-||xi||^2/s^2);  A'[i,j] = exp2(xi*qx[j]+yi*qy[j]+zi*qz[j]+qw[j]),
// q[j] = {2x C, 2y C, 2z C, -||x||^2 C}, C = log2(e)/sigma^2. q planes staged
// in LDS so coord reads ride the lgkm queue (masks = only vmcnt traffic).

#define NN      2048
#define THREADS 512
#define RPB     8            // rows per block = one row per wave
#define EPS     1e-8f

typedef float vf4 __attribute__((ext_vector_type(4)));

__device__ __forceinline__ void stage_q(const float* __restrict__ cb,
                                        float C, float twoC,
                                        float* qx, float* qy, float* qz, float* qw,
                                        int tid)
{
    for (int idx = tid; idx < NN; idx += THREADS) {
        const float x = cb[idx * 3 + 0];
        const float y = cb[idx * 3 + 1];
        const float z = cb[idx * 3 + 2];
        qx[idx] = twoC * x;
        qy[idx] = twoC * y;
        qz[idx] = twoC * z;
        qw[idx] = -C * (x * x + y * y + z * z);
    }
}

// ---------------- K1: row sums (pure read stream) ----------------
__global__ __launch_bounds__(THREADS, 8) void gauss_sum_kernel(
    const float* __restrict__ coords,   // [B, N, 3]
    const float* __restrict__ masks,    // [B, N, N]
    const float* __restrict__ sigma,    // [1]
    float* __restrict__ sums)           // [B*N] (workspace)
{
    const int tid  = threadIdx.x;
    const int wid  = tid >> 6;
    const int lane = tid & 63;
    const int base = blockIdx.x * RPB;
    const int b    = base >> 11;

    __shared__ __align__(16) float qx[NN], qy[NN], qz[NN], qw[NN];

    const float s = sigma[0];
    const float C = 1.44269504088896341f / (s * s);   // log2(e)/sigma^2
    const float* cb = coords + (size_t)b * NN * 3;
    stage_q(cb, C, 2.0f * C, qx, qy, qz, qw, tid);
    __syncthreads();   // only barrier

    const int row = base + wid;
    const int i   = row & (NN - 1);
    const float xi = cb[i * 3 + 0];
    const float yi = cb[i * 3 + 1];
    const float zi = cb[i * 3 + 2];

    const vf4* mrow = (const vf4*)(masks + (size_t)row * NN);
    const vf4* qx4 = (const vf4*)qx;
    const vf4* qy4 = (const vf4*)qy;
    const vf4* qz4 = (const vf4*)qz;
    const vf4* qw4 = (const vf4*)qw;

    float lsum = 0.0f;
    #pragma unroll
    for (int w = 0; w < 8; ++w) {
        const int q_ = w * 64 + lane;
        const vf4 m = mrow[q_];
        const vf4 X = qx4[q_], Y = qy4[q_], Z = qz4[q_], W = qw4[q_];
        lsum += m.x * exp2f(fmaf(xi, X.x, fmaf(yi, Y.x, fmaf(zi, Z.x, W.x))));
        lsum += m.y * exp2f(fmaf(xi, X.y, fmaf(yi, Y.y, fmaf(zi, Z.y, W.y))));
        lsum += m.z * exp2f(fmaf(xi, X.z, fmaf(yi, Y.z, fmaf(zi, Z.z, W.z))));
        lsum += m.w * exp2f(fmaf(xi, X.w, fmaf(yi, Y.w, fmaf(zi, Z.w, W.w))));
    }

    #pragma unroll
    for (int off = 32; off > 0; off >>= 1)
        lsum += __shfl_xor(lsum, off, 64);
    if (lane == 0) sums[row] = lsum;
}

// ---------------- K2: normalize + store (read mostly L3-hot, pure write) ----
__global__ __launch_bounds__(THREADS, 8) void gauss_norm_kernel(
    const float* __restrict__ coords,   // [B, N, 3]
    const float* __restrict__ masks,    // [B, N, N]
    const float* __restrict__ sigma,    // [1]
    const float* __restrict__ sums,     // [B*N]
    float* __restrict__ out)            // [B, N, N]
{
    const int tid  = threadIdx.x;
    const int wid  = tid >> 6;
    const int lane = tid & 63;
    const int base = blockIdx.x * RPB;
    const int b    = base >> 11;

    __shared__ __align__(16) float qx[NN], qy[NN], qz[NN], qw[NN];

    const float s = sigma[0];
    const float C = 1.44269504088896341f / (s * s);
    const float* cb = coords + (size_t)b * NN * 3;
    stage_q(cb, C, 2.0f * C, qx, qy, qz, qw, tid);
    __syncthreads();   // only barrier

    const int row = base + wid;
    const int i   = row & (NN - 1);
    const float xi = cb[i * 3 + 0];
    const float yi = cb[i * 3 + 1];
    const float zi = cb[i * 3 + 2];
    const float inv = 1.0f / (sums[row] + EPS);   // uniform, L2-hot

    const vf4* mrow = (const vf4*)(masks + (size_t)row * NN);
    vf4*       orow = (vf4*)(out + (size_t)row * NN);
    const vf4* qx4 = (const vf4*)qx;
    const vf4* qy4 = (const vf4*)qy;
    const vf4* qz4 = (const vf4*)qz;
    const vf4* qw4 = (const vf4*)qw;

    #pragma unroll
    for (int w = 0; w < 8; ++w) {
        const int q_ = w * 64 + lane;
        const vf4 m = mrow[q_];
        const vf4 X = qx4[q_], Y = qy4[q_], Z = qz4[q_], W = qw4[q_];
        vf4 o;
        o.x = m.x * exp2f(fmaf(xi, X.x, fmaf(yi, Y.x, fmaf(zi, Z.x, W.x)))) * inv;
        o.y = m.y * exp2f(fmaf(xi, X.y, fmaf(yi, Y.y, fmaf(zi, Z.y, W.y)))) * inv;
        o.z = m.z * exp2f(fmaf(xi, X.z, fmaf(yi, Y.z, fmaf(zi, Z.z, W.z)))) * inv;
        o.w = m.w * exp2f(fmaf(xi, X.w, fmaf(yi, Y.w, fmaf(zi, Z.w, W.w)))) * inv;
        __builtin_nontemporal_store(o, &orow[q_]);  // don't evict masks from L3
    }
}

extern "C" void kernel_launch(void* const* d_in, const int* in_sizes, int n_in,
                              void* d_out, int out_size, void* d_ws, size_t ws_size,
                              hipStream_t stream) {
    const float* coords = (const float*)d_in[0];   // [B,N,3]
    const float* masks  = (const float*)d_in[1];   // [B,N,N]
    const float* sigma  = (const float*)d_in[2];   // [1]
    float* out  = (float*)d_out;
    float* sums = (float*)d_ws;                    // rows*4 B = 64 KB

    const int B    = in_sizes[0] / (NN * 3);
    const int rows = B * NN;
    const int grid = rows / RPB;
    gauss_sum_kernel<<<grid, THREADS, 0, stream>>>(coords, masks, sigma, sums);
    gauss_norm_kernel<<<grid, THREADS, 0, stream>>>(coords, masks, sigma, sums, out);
}

// Round 8
// 236.487 us; speedup vs baseline: 1.0896x; 1.0896x over previous
//
#include <hip/hip_runtime.h>
#include <math.h>

// GaussianAdjacencyMatrix: out[b,i,j] = m*exp(-||x_i-x_j||^2/sigma^2) / (row_sum + 1e-8)
// B=8, N=2048, D=3.
//
// v8: R6's A/B two-row pipeline, with the schedule PINNED.
//   R6 post-mortem: VGPR_Count=52 proved the compiler sank row B's loads down
//   to their uses (register-pressure heuristic), silently restoring the serial
//   burst-load -> drain -> burst-store pattern that every variant shares (the
//   row-sum forces outstanding-loads to zero before any store; per-CU average
//   outstanding bytes collapse; ~2.5-3.3 TB/s in all 5 structures).
//   Fix: __builtin_amdgcn_sched_barrier(0) fences between
//   {load A}{load B}{compute+store A}{compute+store B}. With the order pinned,
//   LLVM's precise waitcnt pass emits vmcnt(8) at B's first use (A's 8 stores
//   stay in flight) -> loads and stores finally overlap across rows.
//   Diagnostic: VGPR_Count >= ~90 proves the pipeline survived compilation.
//
// Retained from earlier rounds:
//  - Softmax invariance: A'[i,j] = exp2(xi*qx[j]+yi*qy[j]+zi*qz[j]+qw[j]),
//    q[j] = {2x C, 2y C, 2z C, -||x||^2 C}, C = log2(e)/sigma^2 (row-constant
//    factor cancels in normalization; validated absmax 1.2e-4 since R4).
//  - q planes in LDS (32 KiB): coord reads ride the lgkm queue; masks are the
//    ONLY vmcnt traffic, so counted waits stay simple and precise.
//  - One wave per row: 6-step shfl_xor butterfly, no barrier after staging.
//  - NT mask loads + NT stores (single-use streams; preserve L3).

#define NN      2048
#define THREADS 256
#define ROWS_PER_BLOCK 8          // 4 waves x 2 rows
#define EPS     1e-8f

typedef float vf4 __attribute__((ext_vector_type(4)));

__global__ __launch_bounds__(THREADS, 4) void gauss_adj_kernel(
    const float* __restrict__ coords,   // [B, N, 3]
    const float* __restrict__ masks,    // [B, N, N]
    const float* __restrict__ sigma,    // [1]
    float* __restrict__ out)            // [B, N, N]
{
    const int tid  = threadIdx.x;
    const int wid  = tid >> 6;
    const int lane = tid & 63;
    const int base = blockIdx.x * ROWS_PER_BLOCK;   // 8 consecutive rows, same batch
    const int b    = base >> 11;

    __shared__ __align__(16) float qx[NN];
    __shared__ __align__(16) float qy[NN];
    __shared__ __align__(16) float qz[NN];
    __shared__ __align__(16) float qw[NN];

    const float s = sigma[0];
    const float C = 1.44269504088896341f / (s * s);   // log2(e)/sigma^2
    const float twoC = 2.0f * C;
    const float* cb = coords + (size_t)b * NN * 3;

    for (int idx = tid; idx < NN; idx += THREADS) {
        const float x = cb[idx * 3 + 0];
        const float y = cb[idx * 3 + 1];
        const float z = cb[idx * 3 + 2];
        qx[idx] = twoC * x;
        qy[idx] = twoC * y;
        qz[idx] = twoC * z;
        qw[idx] = -C * (x * x + y * y + z * z);
    }
    __syncthreads();   // the only barrier

    const vf4* qx4 = (const vf4*)qx;
    const vf4* qy4 = (const vf4*)qy;
    const vf4* qz4 = (const vf4*)qz;
    const vf4* qw4 = (const vf4*)qw;

    const int rA = base + wid * 2 + 0;
    const int rB = base + wid * 2 + 1;

    const vf4* mA = (const vf4*)(masks + (size_t)rA * NN);
    const vf4* mB = (const vf4*)(masks + (size_t)rB * NN);

    vf4 va[8], vb[8];

    // --- phase 1: issue ALL 16 mask loads (both rows), order pinned ---
    #pragma unroll
    for (int w = 0; w < 8; ++w)
        va[w] = __builtin_nontemporal_load(&mA[w * 64 + lane]);
    __builtin_amdgcn_sched_barrier(0);
    #pragma unroll
    for (int w = 0; w < 8; ++w)
        vb[w] = __builtin_nontemporal_load(&mB[w * 64 + lane]);
    __builtin_amdgcn_sched_barrier(0);

#define PROC(BUF, ROW) { \
    const int i_ = (ROW) & (NN - 1); \
    const float xi = cb[i_ * 3 + 0]; \
    const float yi = cb[i_ * 3 + 1]; \
    const float zi = cb[i_ * 3 + 2]; \
    float lsum = 0.0f; \
    _Pragma("unroll") \
    for (int w = 0; w < 8; ++w) { \
        const int q_ = w * 64 + lane; \
        const vf4 X = qx4[q_], Y = qy4[q_], Z = qz4[q_], W = qw4[q_]; \
        vf4 v = BUF[w]; \
        v.x *= exp2f(fmaf(xi, X.x, fmaf(yi, Y.x, fmaf(zi, Z.x, W.x)))); \
        v.y *= exp2f(fmaf(xi, X.y, fmaf(yi, Y.y, fmaf(zi, Z.y, W.y)))); \
        v.z *= exp2f(fmaf(xi, X.z, fmaf(yi, Y.z, fmaf(zi, Z.z, W.z)))); \
        v.w *= exp2f(fmaf(xi, X.w, fmaf(yi, Y.w, fmaf(zi, Z.w, W.w)))); \
        BUF[w] = v; \
        lsum += (v.x + v.y) + (v.z + v.w); \
    } \
    _Pragma("unroll") \
    for (int off = 32; off > 0; off >>= 1) \
        lsum += __shfl_xor(lsum, off, 64); \
    const float inv_ = 1.0f / (lsum + EPS); \
    vf4* orow_ = (vf4*)(out + (size_t)(ROW) * NN); \
    _Pragma("unroll") \
    for (int w = 0; w < 8; ++w) { \
        vf4 o = BUF[w]; \
        o.x *= inv_; o.y *= inv_; o.z *= inv_; o.w *= inv_; \
        __builtin_nontemporal_store(o, &orow_[w * 64 + lane]); \
    } }

    // --- phase 2: compute+store A (B's loads in flight; waitcnt for A = vmcnt(8)) ---
    PROC(va, rA)
    __builtin_amdgcn_sched_barrier(0);
    // --- phase 3: compute+store B (first use of vb waits vmcnt(8): A's stores fly) ---
    PROC(vb, rB)
#undef PROC
}

extern "C" void kernel_launch(void* const* d_in, const int* in_sizes, int n_in,
                              void* d_out, int out_size, void* d_ws, size_t ws_size,
                              hipStream_t stream) {
    const float* coords = (const float*)d_in[0];   // [B,N,3]
    const float* masks  = (const float*)d_in[1];   // [B,N,N]
    const float* sigma  = (const float*)d_in[2];   // [1]
    float* out = (float*)d_out;

    const int B    = in_sizes[0] / (NN * 3);
    const int rows = B * NN;
    gauss_adj_kernel<<<rows / ROWS_PER_BLOCK, THREADS, 0, stream>>>(coords, masks, sigma, out);
}